// Round 12
// baseline (971.772 us; speedup 1.0000x reference)
//
#include <hip/hip_runtime.h>
#include <hip/hip_bf16.h>
#include <math.h>

#define T_TOK 2048
#define H_DIM 2048
#define E_NUM 64
#define F_DIM 512
#define K_TOP 8
#define FS_DIM 512
#define NROWS (T_TOK * K_TOP)

typedef __attribute__((ext_vector_type(8))) short short8v;   // bf16x8 MFMA frag
typedef __attribute__((ext_vector_type(4))) float f32x4;     // MFMA accum

static __device__ __forceinline__ unsigned short f2bf(float f) {
    unsigned int u = __float_as_uint(f);
    u += 0x7fff + ((u >> 16) & 1);           // RNE to bf16
    return (unsigned short)(u >> 16);
}

// B tile [64 n][64 k]: 16B-chunk XOR swizzle (proven rounds 5/6/9-11)
#define BCHUNK(row, k8) ((((k8) ^ ((row) + ((row) >> 3)))) & 7)

// raw barrier: LDS ops drained; plain global loads unaffected (no GLDS here,
// so no vmcnt discipline is needed — ds ordering enforced by "memory" clobber)
#define PIPE_BARRIER() do { \
    asm volatile("s_waitcnt lgkmcnt(0)" ::: "memory"); \
    __builtin_amdgcn_s_barrier(); \
} while (0)

// ---------------------------------------------------------------------------
// x (fp32) -> bf16 copy, vectorized 8/thread
// ---------------------------------------------------------------------------
__global__ __launch_bounds__(256) void cvt_bf16_kernel(
    const float* __restrict__ in, unsigned short* __restrict__ out, int n8)
{
    int i = blockIdx.x * 256 + threadIdx.x;
    if (i < n8) {
        const float4* p = (const float4*)(in + (size_t)i * 8);
        float4 v0 = p[0], v1 = p[1];
        ushort4 a = make_ushort4(f2bf(v0.x), f2bf(v0.y), f2bf(v0.z), f2bf(v0.w));
        ushort4 b = make_ushort4(f2bf(v1.x), f2bf(v1.y), f2bf(v1.z), f2bf(v1.w));
        ushort4* q = (ushort4*)(out + (size_t)i * 8);
        q[0] = a; q[1] = b;
    }
}

// ---------------------------------------------------------------------------
// Router: one wave per token (fp32 math, exact top-k vs reference).
// ---------------------------------------------------------------------------
__global__ __launch_bounds__(64) void router_kernel(
    const float* __restrict__ x, const float* __restrict__ Wg,
    int* __restrict__ topk_idx, float* __restrict__ topk_w,
    float* __restrict__ sgate, int* __restrict__ counts)
{
    const int t = blockIdx.x;
    const int lane = threadIdx.x;
    const float* xr = x + (size_t)t * H_DIM;

    float a0 = 0.f, a1 = 0.f, a2 = 0.f, a3 = 0.f;
    for (int h = 0; h < H_DIM; h += 4) {
        float4 xv = *(const float4*)&xr[h];
        a0 += xv.x * Wg[(h + 0) * 65 + lane];
        a1 += xv.y * Wg[(h + 1) * 65 + lane];
        a2 += xv.z * Wg[(h + 2) * 65 + lane];
        a3 += xv.w * Wg[(h + 3) * 65 + lane];
    }
    float logit = (a0 + a1) + (a2 + a3);

    float a64 = 0.f;
    for (int h = lane; h < H_DIM; h += 64) a64 += xr[h] * Wg[h * 65 + 64];
#pragma unroll
    for (int off = 32; off >= 1; off >>= 1) a64 += __shfl_xor(a64, off);

    float v = logit;
    float selv[K_TOP]; int seli[K_TOP];
#pragma unroll
    for (int k = 0; k < K_TOP; ++k) {
        float mv = v; int mi = lane;
#pragma unroll
        for (int off = 32; off >= 1; off >>= 1) {
            float ov = __shfl_xor(mv, off);
            int   oi = __shfl_xor(mi, off);
            if (ov > mv || (ov == mv && oi < mi)) { mv = ov; mi = oi; }
        }
        selv[k] = mv; seli[k] = mi;
        if (lane == mi) v = -INFINITY;
    }

    if (lane == 0) {
        float m = selv[0];
        float w[K_TOP]; float s = 0.f;
#pragma unroll
        for (int k = 0; k < K_TOP; ++k) { w[k] = __expf(selv[k] - m); s += w[k]; }
        float inv = 1.f / s;
#pragma unroll
        for (int k = 0; k < K_TOP; ++k) {
            topk_idx[t * K_TOP + k] = seli[k];
            topk_w[t * K_TOP + k] = w[k] * inv;
            atomicAdd(&counts[seli[k]], 1);
        }
        sgate[t] = 1.f / (1.f + __expf(-a64));
    }
}

// ---------------------------------------------------------------------------
// Deterministic per-expert compaction.
// ---------------------------------------------------------------------------
__global__ __launch_bounds__(256) void bucket_kernel(
    const int* __restrict__ topk_idx, const float* __restrict__ topk_w,
    const int* __restrict__ counts, int* __restrict__ offsets,
    int* __restrict__ bucket_tok, float* __restrict__ bucket_w)
{
    const int e = blockIdx.x, thr = threadIdx.x;
    __shared__ int cnt[256];
    __shared__ int base_s;
    const int q0 = thr * 64;
    int c = 0;
    for (int q = 0; q < 64; ++q) c += (topk_idx[q0 + q] == e) ? 1 : 0;
    cnt[thr] = c;
    __syncthreads();
    if (thr == 0) {
        int off = 0;
        for (int i = 0; i < e; ++i) off += counts[i];
        offsets[e] = off;
        base_s = off;
        int run = 0;
        for (int i = 0; i < 256; ++i) { int tval = cnt[i]; cnt[i] = run; run += tval; }
    }
    __syncthreads();
    int pos = base_s + cnt[thr];
    for (int q = 0; q < 64; ++q) {
        int pp = q0 + q;
        if (topk_idx[pp] == e) {
            bucket_tok[pos] = pp >> 3;
            bucket_w[pos] = topk_w[pp];
            ++pos;
        }
    }
}

// ---------------------------------------------------------------------------
// gate_up + SiLU*u*topw — A-frags DIRECT from global bf16 (no LDS A, no GLDS,
// no vmcnt discipline). Explicit frag double-buffer: afp (ks0 of next kt)
// reloaded between the two MFMA half-blocks; af1 (ks1 of current kt) loaded
// at step top. sched_barrier(0) pins load issue before the MFMA clusters so
// the compiler cannot sink them into serial load->use chains (round-5/6 bug).
// B: W fp32->bf16 reg-transposed into LDS dbuf (proven), one barrier per K64.
// Block 512 thr = 8 waves (4 wm x 2 wn); BM=256, BN=32 act cols; acc[4][2].
// ---------------------------------------------------------------------------
template<bool ROUTED>
__global__ __launch_bounds__(512, 4) void gu_mfma_kernel(
    const unsigned short* __restrict__ xb,
    const float* __restrict__ Wall,
    const int* __restrict__ counts, const int* __restrict__ offsets,
    const int* __restrict__ bucket_tok, const float* __restrict__ bucket_w,
    unsigned short* __restrict__ actout)
{
    constexpr int BM = 256;
    __shared__ __align__(16) unsigned short Bs[2][64 * 64];  // 2 x 8 KB
    __shared__ int   toksS[BM];
    __shared__ float twsS[BM];

    const int tid  = threadIdx.x;
    const int lane = tid & 63;
    const int wid  = tid >> 6;
    const int wm = wid >> 1, wn = wid & 1;
    const int lrow = lane & 15, lhi = lane >> 4;

    int cblk, ne, base;
    const float* W;
    if (ROUTED) {
        int nw = (blockIdx.x & 7) * ((int)gridDim.x >> 3) + (blockIdx.x >> 3);
        int e = nw >> 4; cblk = nw & 15;
        ne = counts[e]; base = offsets[e];
        W = Wall + (size_t)e * H_DIM * (2 * F_DIM);
    } else {
        cblk = blockIdx.x;
        ne = T_TOK; base = 0;
        W = Wall;
    }
    const int c0 = cblk * 32;               // act-col base

    // W staging geometry: thread covers 4 n-cols x 2 k-rows (proven round 6)
    const int n4 = (tid & 15) * 4;
    const int kb = (tid >> 4) * 2;
    const int n5 = n4 & 31;
    const int wcol = ((n5 < 16) ? 0 : (F_DIM - 16)) + c0 + (n4 >> 5) * 16 + n5;
    int wr_off[4];
#pragma unroll
    for (int cc = 0; cc < 4; ++cc) {
        int n = n4 + cc;
        wr_off[cc] = n * 64 + BCHUNK(n, kb >> 3) * 8 + (kb & 7);
    }
    const int rg = wn * 32 + lrow, ru = wn * 32 + 16 + lrow;
    int rd_g[2], rd_u[2];
#pragma unroll
    for (int ks = 0; ks < 2; ++ks) {
        int kc = ks * 4 + lhi;
        rd_g[ks] = rg * 64 + BCHUNK(rg, kc) * 8;
        rd_u[ks] = ru * 64 + BCHUNK(ru, kc) * 8;
    }

    const int m0_beg = ROUTED ? 0 : blockIdx.y * BM;
    const int m0_end = ROUTED ? ne : m0_beg + BM;
    const int NT = H_DIM / 64;

    for (int m0 = m0_beg; m0 < m0_end; m0 += BM) {
        __syncthreads();
        if (tid < BM) {
            int idx = m0 + tid; bool v = idx < ne;
            if (ROUTED) {
                toksS[tid] = v ? bucket_tok[base + idx] : bucket_tok[base];
                twsS[tid]  = v ? bucket_w[base + idx] : 0.f;
            } else {
                toksS[tid] = v ? idx : (T_TOK - 1);
                twsS[tid]  = 1.f;
            }
        }
        __syncthreads();

        const unsigned short* aptr[4];
#pragma unroll
        for (int fm = 0; fm < 4; ++fm) {
            int r = wm * 64 + fm * 16 + lrow;
            aptr[fm] = xb + (size_t)toksS[r] * H_DIM;
        }

        f32x4 acc[4][2];
#pragma unroll
        for (int i = 0; i < 4; ++i) {
            acc[i][0] = (f32x4){0.f, 0.f, 0.f, 0.f};
            acc[i][1] = (f32x4){0.f, 0.f, 0.f, 0.f};
        }

        // prologue: B(0)->Bs[0]; bq=W(1); afp = A(kt0, ks0)
        float4 b0 = *(const float4*)&W[(size_t)kb * (2 * F_DIM) + wcol];
        float4 b1 = *(const float4*)&W[(size_t)(kb + 1) * (2 * F_DIM) + wcol];
#pragma unroll
        for (int cc = 0; cc < 4; ++cc)
            *(ushort2*)&Bs[0][wr_off[cc]] = make_ushort2(
                f2bf(((const float*)&b0)[cc]), f2bf(((const float*)&b1)[cc]));
        b0 = *(const float4*)&W[(size_t)(64 + kb) * (2 * F_DIM) + wcol];
        b1 = *(const float4*)&W[(size_t)(64 + kb + 1) * (2 * F_DIM) + wcol];
        short8v afp[4];
#pragma unroll
        for (int fm = 0; fm < 4; ++fm)
            afp[fm] = *(const short8v*)(aptr[fm] + lhi * 8);
        PIPE_BARRIER();

        for (int kt = 0; kt < NT; ++kt) {
            const int k0 = kt * 64;
            // stage B(kt+1); prefetch W(kt+2)
            if (kt + 1 < NT) {
                unsigned short* nB = Bs[(kt + 1) & 1];
#pragma unroll
                for (int cc = 0; cc < 4; ++cc)
                    *(ushort2*)&nB[wr_off[cc]] = make_ushort2(
                        f2bf(((const float*)&b0)[cc]), f2bf(((const float*)&b1)[cc]));
                int knx = (kt + 2 < NT) ? (k0 + 128) : (k0 + 64);
                b0 = *(const float4*)&W[(size_t)(knx + kb) * (2 * F_DIM) + wcol];
                b1 = *(const float4*)&W[(size_t)(knx + kb + 1) * (2 * F_DIM) + wcol];
            }
            // af1 = A(kt, ks1) — issue before MFMA cluster
            short8v af1[4];
#pragma unroll
            for (int fm = 0; fm < 4; ++fm)
                af1[fm] = *(const short8v*)(aptr[fm] + k0 + (4 + lhi) * 8);
            __builtin_amdgcn_sched_barrier(0);
            // ks0 MFMAs on afp
            {
                const unsigned short* B_ = Bs[kt & 1];
                short8v bg = *(const short8v*)&B_[rd_g[0]];
                short8v bu = *(const short8v*)&B_[rd_u[0]];
#pragma unroll
                for (int fm = 0; fm < 4; ++fm) {
                    acc[fm][0] = __builtin_amdgcn_mfma_f32_16x16x32_bf16(afp[fm], bg, acc[fm][0], 0, 0, 0);
                    acc[fm][1] = __builtin_amdgcn_mfma_f32_16x16x32_bf16(afp[fm], bu, acc[fm][1], 0, 0, 0);
                }
            }
            // reload afp = A(kt+1, ks0) — latency hides under ks1 MFMAs + barrier
            if (kt + 1 < NT) {
#pragma unroll
                for (int fm = 0; fm < 4; ++fm)
                    afp[fm] = *(const short8v*)(aptr[fm] + k0 + 64 + lhi * 8);
            }
            __builtin_amdgcn_sched_barrier(0);
            // ks1 MFMAs on af1
            {
                const unsigned short* B_ = Bs[kt & 1];
                short8v bg = *(const short8v*)&B_[rd_g[1]];
                short8v bu = *(const short8v*)&B_[rd_u[1]];
#pragma unroll
                for (int fm = 0; fm < 4; ++fm) {
                    acc[fm][0] = __builtin_amdgcn_mfma_f32_16x16x32_bf16(af1[fm], bg, acc[fm][0], 0, 0, 0);
                    acc[fm][1] = __builtin_amdgcn_mfma_f32_16x16x32_bf16(af1[fm], bu, acc[fm][1], 0, 0, 0);
                }
            }
            PIPE_BARRIER();
        }

        // epilogue: silu(g)*u*topw -> bf16 act
        const int acol = c0 + wn * 16 + lrow;
#pragma unroll
        for (int fm = 0; fm < 4; ++fm) {
#pragma unroll
            for (int i = 0; i < 4; ++i) {
                int ml = wm * 64 + fm * 16 + lhi * 4 + i;
                int idx = m0 + ml;
                if (idx < ne) {
                    float gv = acc[fm][0][i], uv = acc[fm][1][i];
                    float s = gv / (1.f + __expf(-gv));
                    float val = s * uv * twsS[ml];
                    size_t orow = ROUTED ? (size_t)(base + idx) : (size_t)idx;
                    actout[orow * F_DIM + acol] = f2bf(val);
                }
            }
        }
    }
}

// ---------------------------------------------------------------------------
// down-proj — same direct-A structure. A rows contiguous (packed act).
// BN=64 out cols; acc[4][2]; NT=8. ROUTED: atomicAdd; shared: store*sigmoid.
// ---------------------------------------------------------------------------
template<bool ROUTED>
__global__ __launch_bounds__(512, 4) void down_mfma_kernel(
    const unsigned short* __restrict__ actb,
    const float* __restrict__ Wall,
    const int* __restrict__ counts, const int* __restrict__ offsets,
    const int* __restrict__ bucket_tok, const float* __restrict__ sgate,
    float* __restrict__ out)
{
    constexpr int BM = 256;
    __shared__ __align__(16) unsigned short Bs[2][64 * 64];
    __shared__ int   toksS[BM];
    __shared__ float sgS[BM];

    const int tid  = threadIdx.x;
    const int lane = tid & 63;
    const int wid  = tid >> 6;
    const int wm = wid >> 1, wn = wid & 1;
    const int lrow = lane & 15, lhi = lane >> 4;

    int cblk, ne, base;
    const float* W;
    if (ROUTED) {
        int nw = (blockIdx.x & 7) * ((int)gridDim.x >> 3) + (blockIdx.x >> 3);
        int e = nw >> 5; cblk = nw & 31;
        ne = counts[e]; base = offsets[e];
        W = Wall + (size_t)e * F_DIM * H_DIM;
    } else {
        cblk = blockIdx.x;
        ne = T_TOK; base = 0;
        W = Wall;
    }
    const int c0 = cblk * 64;

    const int n4 = (tid & 15) * 4;
    const int kb = (tid >> 4) * 2;
    const int wcol = c0 + n4;
    int wr_off[4];
#pragma unroll
    for (int cc = 0; cc < 4; ++cc) {
        int n = n4 + cc;
        wr_off[cc] = n * 64 + BCHUNK(n, kb >> 3) * 8 + (kb & 7);
    }
    const int r0 = wn * 32 + lrow, r1 = wn * 32 + 16 + lrow;
    int rd_0[2], rd_1[2];
#pragma unroll
    for (int ks = 0; ks < 2; ++ks) {
        int kc = ks * 4 + lhi;
        rd_0[ks] = r0 * 64 + BCHUNK(r0, kc) * 8;
        rd_1[ks] = r1 * 64 + BCHUNK(r1, kc) * 8;
    }

    const int m0_beg = ROUTED ? 0 : blockIdx.y * BM;
    const int m0_end = ROUTED ? ne : m0_beg + BM;
    const int NT = F_DIM / 64;

    for (int m0 = m0_beg; m0 < m0_end; m0 += BM) {
        __syncthreads();
        if (tid < BM) {
            int idx = m0 + tid;
            if (ROUTED) {
                toksS[tid] = (idx < ne) ? bucket_tok[base + idx] : 0;
            } else {
                sgS[tid] = sgate[(idx < ne) ? idx : (T_TOK - 1)];
            }
        }
        __syncthreads();

        const unsigned short* aptr[4];
#pragma unroll
        for (int fm = 0; fm < 4; ++fm) {
            int r = wm * 64 + fm * 16 + lrow;
            int grow = ROUTED ? min(base + m0 + r, NROWS - 1) : min(m0 + r, T_TOK - 1);
            aptr[fm] = actb + (size_t)grow * F_DIM;
        }

        f32x4 acc[4][2];
#pragma unroll
        for (int i = 0; i < 4; ++i) {
            acc[i][0] = (f32x4){0.f, 0.f, 0.f, 0.f};
            acc[i][1] = (f32x4){0.f, 0.f, 0.f, 0.f};
        }

        float4 b0 = *(const float4*)&W[(size_t)kb * H_DIM + wcol];
        float4 b1 = *(const float4*)&W[(size_t)(kb + 1) * H_DIM + wcol];
#pragma unroll
        for (int cc = 0; cc < 4; ++cc)
            *(ushort2*)&Bs[0][wr_off[cc]] = make_ushort2(
                f2bf(((const float*)&b0)[cc]), f2bf(((const float*)&b1)[cc]));
        b0 = *(const float4*)&W[(size_t)(64 + kb) * H_DIM + wcol];
        b1 = *(const float4*)&W[(size_t)(64 + kb + 1) * H_DIM + wcol];
        short8v afp[4];
#pragma unroll
        for (int fm = 0; fm < 4; ++fm)
            afp[fm] = *(const short8v*)(aptr[fm] + lhi * 8);
        PIPE_BARRIER();

        for (int kt = 0; kt < NT; ++kt) {
            const int k0 = kt * 64;
            if (kt + 1 < NT) {
                unsigned short* nB = Bs[(kt + 1) & 1];
#pragma unroll
                for (int cc = 0; cc < 4; ++cc)
                    *(ushort2*)&nB[wr_off[cc]] = make_ushort2(
                        f2bf(((const float*)&b0)[cc]), f2bf(((const float*)&b1)[cc]));
                int knx = (kt + 2 < NT) ? (k0 + 128) : (k0 + 64);
                b0 = *(const float4*)&W[(size_t)(knx + kb) * H_DIM + wcol];
                b1 = *(const float4*)&W[(size_t)(knx + kb + 1) * H_DIM + wcol];
            }
            short8v af1[4];
#pragma unroll
            for (int fm = 0; fm < 4; ++fm)
                af1[fm] = *(const short8v*)(aptr[fm] + k0 + (4 + lhi) * 8);
            __builtin_amdgcn_sched_barrier(0);
            {
                const unsigned short* B_ = Bs[kt & 1];
                short8v bf0 = *(const short8v*)&B_[rd_0[0]];
                short8v bf1 = *(const short8v*)&B_[rd_1[0]];
#pragma unroll
                for (int fm = 0; fm < 4; ++fm) {
                    acc[fm][0] = __builtin_amdgcn_mfma_f32_16x16x32_bf16(afp[fm], bf0, acc[fm][0], 0, 0, 0);
                    acc[fm][1] = __builtin_amdgcn_mfma_f32_16x16x32_bf16(afp[fm], bf1, acc[fm][1], 0, 0, 0);
                }
            }
            if (kt + 1 < NT) {
#pragma unroll
                for (int fm = 0; fm < 4; ++fm)
                    afp[fm] = *(const short8v*)(aptr[fm] + k0 + 64 + lhi * 8);
            }
            __builtin_amdgcn_sched_barrier(0);
            {
                const unsigned short* B_ = Bs[kt & 1];
                short8v bf0 = *(const short8v*)&B_[rd_0[1]];
                short8v bf1 = *(const short8v*)&B_[rd_1[1]];
#pragma unroll
                for (int fm = 0; fm < 4; ++fm) {
                    acc[fm][0] = __builtin_amdgcn_mfma_f32_16x16x32_bf16(af1[fm], bf0, acc[fm][0], 0, 0, 0);
                    acc[fm][1] = __builtin_amdgcn_mfma_f32_16x16x32_bf16(af1[fm], bf1, acc[fm][1], 0, 0, 0);
                }
            }
            PIPE_BARRIER();
        }

#pragma unroll
        for (int fm = 0; fm < 4; ++fm) {
#pragma unroll
            for (int fn = 0; fn < 2; ++fn) {
                int col = c0 + wn * 32 + fn * 16 + lrow;
#pragma unroll
                for (int i = 0; i < 4; ++i) {
                    int ml = wm * 64 + fm * 16 + lhi * 4 + i;
                    int idx = m0 + ml;
                    if (idx < ne) {
                        if (ROUTED) {
                            atomicAdd(&out[(size_t)toksS[ml] * H_DIM + col], acc[fm][fn][i]);
                        } else {
                            out[(size_t)idx * H_DIM + col] = sgS[ml] * acc[fm][fn][i];
                        }
                    }
                }
            }
        }
    }
}

// ---------------------------------------------------------------------------
extern "C" void kernel_launch(void* const* d_in, const int* in_sizes, int n_in,
                              void* d_out, int out_size, void* d_ws, size_t ws_size,
                              hipStream_t stream) {
    const float* x    = (const float*)d_in[0];
    const float* Wg   = (const float*)d_in[1];
    const float* Wgu  = (const float*)d_in[2];
    const float* Wd   = (const float*)d_in[3];
    const float* Wsgu = (const float*)d_in[4];
    const float* Wsd  = (const float*)d_in[5];
    float* out = (float*)d_out;

    char* p = (char*)d_ws;
    auto alloc = [&](size_t bytes) {
        char* r = p;
        p += (bytes + 255) & ~(size_t)255;
        return r;
    };
    int*   topk_idx   = (int*)  alloc((size_t)T_TOK * K_TOP * sizeof(int));
    float* topk_w     = (float*)alloc((size_t)T_TOK * K_TOP * sizeof(float));
    float* sgate      = (float*)alloc((size_t)T_TOK * sizeof(float));
    int*   counts     = (int*)  alloc((size_t)E_NUM * sizeof(int));
    int*   offsets    = (int*)  alloc((size_t)E_NUM * sizeof(int));
    int*   bucket_tok = (int*)  alloc((size_t)NROWS * sizeof(int));
    float* bucket_w   = (float*)alloc((size_t)NROWS * sizeof(float));
    unsigned short* xb    = (unsigned short*)alloc((size_t)T_TOK * H_DIM * sizeof(short));
    unsigned short* act_r = (unsigned short*)alloc((size_t)NROWS * F_DIM * sizeof(short));
    unsigned short* act_s = (unsigned short*)alloc((size_t)T_TOK * FS_DIM * sizeof(short));

    hipMemsetAsync(counts, 0, E_NUM * sizeof(int), stream);
    cvt_bf16_kernel<<<(T_TOK * H_DIM / 8 + 255) / 256, 256, 0, stream>>>(x, xb, T_TOK * H_DIM / 8);
    router_kernel<<<T_TOK, 64, 0, stream>>>(x, Wg, topk_idx, topk_w, sgate, counts);
    bucket_kernel<<<E_NUM, 256, 0, stream>>>(topk_idx, topk_w, counts, offsets, bucket_tok, bucket_w);

    // shared gate_up first (linear x reads warm L2/L3 for the gathered reads)
    gu_mfma_kernel<false><<<dim3(16, T_TOK / 256), 512, 0, stream>>>(
        xb, Wsgu, counts, offsets, bucket_tok, bucket_w, act_s);
    // routed gate_up: 16 colblks x 64 experts, in-block m-loop (no parasite blocks)
    gu_mfma_kernel<true><<<16 * E_NUM, 512, 0, stream>>>(
        xb, Wgu, counts, offsets, bucket_tok, bucket_w, act_r);

    // shared down writes out first; routed down accumulates atomically on top
    down_mfma_kernel<false><<<dim3(32, T_TOK / 256), 512, 0, stream>>>(
        act_s, Wsd, counts, offsets, bucket_tok, sgate, out);
    down_mfma_kernel<true><<<32 * E_NUM, 512, 0, stream>>>(
        act_r, Wd, counts, offsets, bucket_tok, sgate, out);
}